// Round 1
// baseline (400.819 us; speedup 1.0000x reference)
//
#include <hip/hip_runtime.h>

#define DEV __device__ __forceinline__

typedef __attribute__((ext_vector_type(8))) short bf16x8;   // 8 bf16 in 4 VGPRs
typedef __attribute__((ext_vector_type(4))) float f32x4;

constexpr int Bc  = 32;
constexpr int Nc  = 512;
constexpr int Dc  = 1024;
constexpr int Hc  = 16;
constexpr int HDc = 64;
constexpr int SEGc= 64;
constexpr int Mrows = Bc * Nc;          // 16384 rows for the big GEMMs

// round-to-nearest-even f32 -> bf16 bit pattern
DEV unsigned short bf16r(float x) {
  union { float f; unsigned int u; } c; c.f = x;
  unsigned int r = (c.u + 0x7fffu + ((c.u >> 16) & 1u)) >> 16;
  return (unsigned short)r;
}

// async global->LDS, 16B per lane. LDS dest must be wave-uniform base; HW
// scatters lane i to base + i*16 (guide §5 caveat m104/m108).
DEV void async_ld16(const void* g, void* l) {
  __builtin_amdgcn_global_load_lds(
      (const __attribute__((address_space(1))) void*)g,
      (__attribute__((address_space(3))) void*)l,
      16, 0, 0);
}

// ---------------------------------------------------------------- converts
__global__ void cvt_bf16(const float* __restrict__ src,
                         unsigned short* __restrict__ dst, int n4) {
  int i = blockIdx.x * blockDim.x + threadIdx.x;
  if (i >= n4) return;
  float4 v = ((const float4*)src)[i];
  ushort4 o;
  o.x = bf16r(v.x); o.y = bf16r(v.y); o.z = bf16r(v.z); o.w = bf16r(v.w);
  ((ushort4*)dst)[i] = o;
}

// transpose 1024x1024 f32 -> bf16 (dst[c][r] = src[r][c])
__global__ void transpose_bf16(const float* __restrict__ src,
                               unsigned short* __restrict__ dst) {
  __shared__ float tile[32][33];
  int bx = blockIdx.x & 31, by = blockIdx.x >> 5;
  int tx = threadIdx.x & 31, ty = threadIdx.x >> 5;   // 32 x 8
  for (int i = 0; i < 4; ++i) {
    int r = ty + i * 8;
    tile[r][tx] = src[(size_t)(by * 32 + r) * 1024 + bx * 32 + tx];
  }
  __syncthreads();
  for (int i = 0; i < 4; ++i) {
    int r = ty + i * 8;
    dst[(size_t)(bx * 32 + r) * 1024 + by * 32 + tx] = bf16r(tile[tx][r]);
  }
}

// ---------------------------------------------------------------- GEMM
// C(M x 1024) = A(M x 1024, bf16 row-major) * B + bias; B given as BT (1024 x 1024
// bf16 row-major, BT[n][k] = B[k][n]). OUT_F32: f32 out, else bf16 out.
template <bool OUT_F32>
__global__ __launch_bounds__(256)
void gemm_bt(const unsigned short* __restrict__ A,
             const unsigned short* __restrict__ BT,
             const float* __restrict__ bias,
             void* __restrict__ Cout) {
  constexpr int K = 1024, Nn = 1024, BM = 128, BN = 128, BK = 32;
  __shared__ unsigned short As[BM * BK];   // row-major [128][32]
  __shared__ unsigned short Bs[BN * BK];   // row-major [128][32] (rows = n)
  const int tid = threadIdx.x, lane = tid & 63, wave = tid >> 6;
  const int tm = blockIdx.x >> 3, tn = blockIdx.x & 7;   // Nn/BN = 8
  const int wm = (wave >> 1) * 64, wn = (wave & 1) * 64; // 2x2 waves, 64x64 each
  const int la = lane & 15, lb8 = (lane >> 4) * 8;

  f32x4 acc[4][4] = {};

  const int srow = tid >> 2;          // 0..63 (staging row, pass 0)
  const int scol = (tid & 3) * 8;     // element col offset (16B chunks)
  const unsigned short* Ag = A  + (size_t)(tm * BM + srow) * K + scol;
  const unsigned short* Bg = BT + (size_t)(tn * BN + srow) * K + scol;
  unsigned short* ldsA = As + wave * 512;   // wave-uniform base (bytes wave*1024)
  unsigned short* ldsB = Bs + wave * 512;

  for (int k0 = 0; k0 < K; k0 += BK) {
    __syncthreads();                       // prev tile fully consumed
    async_ld16(Ag + k0,          ldsA);
    async_ld16(Ag + 64 * K + k0, ldsA + 2048);
    async_ld16(Bg + k0,          ldsB);
    async_ld16(Bg + 64 * K + k0, ldsB + 2048);
    __syncthreads();                       // vmcnt(0) drain before barrier

    bf16x8 af[4], bfr[4];
#pragma unroll
    for (int i = 0; i < 4; ++i)
      af[i] = *(const bf16x8*)(As + (wm + i * 16 + la) * BK + lb8);
#pragma unroll
    for (int j = 0; j < 4; ++j)
      bfr[j] = *(const bf16x8*)(Bs + (wn + j * 16 + la) * BK + lb8);
#pragma unroll
    for (int i = 0; i < 4; ++i)
#pragma unroll
      for (int j = 0; j < 4; ++j)
        acc[i][j] = __builtin_amdgcn_mfma_f32_16x16x32_bf16(af[i], bfr[j],
                                                            acc[i][j], 0, 0, 0);
  }

  // epilogue: C/D layout row = (lane>>4)*4 + r, col = lane&15 (m89-verified)
  const int colbase = tn * BN + wn;
  float bv[4];
#pragma unroll
  for (int j = 0; j < 4; ++j) bv[j] = bias[colbase + j * 16 + la];
#pragma unroll
  for (int i = 0; i < 4; ++i) {
    int row0 = tm * BM + wm + i * 16 + (lane >> 4) * 4;
#pragma unroll
    for (int j = 0; j < 4; ++j) {
      int col = colbase + j * 16 + la;
#pragma unroll
      for (int r = 0; r < 4; ++r) {
        float v = acc[i][j][r] + bv[j];
        size_t idx = (size_t)(row0 + r) * Nn + col;
        if (OUT_F32) ((float*)Cout)[idx] = v;
        else         ((unsigned short*)Cout)[idx] = bf16r(v);
      }
    }
  }
}

// ---------------------------------------------------------------- middle
// One block per n. scores = Q_n(512x64) @ R_n^T ; softmax over s ; recv = A @ R_n.
// Q rows m = b*16+h; an m-tile of 16 rows = one b, h=0..15.
__global__ __launch_bounds__(256)
void router_mid(const unsigned short* __restrict__ qb,       // (16384 x 1024) bf16
                const unsigned short* __restrict__ routerb,  // (64 x 512 x 64) bf16
                float* __restrict__ attn_out,                // (B,H,N,S) f32
                unsigned short* __restrict__ recv_out) {     // (16384 x 1024) bf16
  __shared__ unsigned short Rs [SEGc * HDc];   // R[s][d]
  __shared__ unsigned short RTs[HDc * SEGc];   // R^T[d][s]
  __shared__ unsigned short AT [4 * 16 * 64];  // per-wave attn tile (A-layout src)

  const int n = blockIdx.x;
  const int tid = threadIdx.x, lane = tid & 63, wave = tid >> 6;
  const int la = lane & 15, lb8 = (lane >> 4) * 8;

  // stage R: rows s, 64 bf16 each; async 16B/lane, 2 passes
  {
    int s  = tid >> 3;             // 0..31
    int c8 = (tid & 7) * 8;
    async_ld16(routerb + ((size_t)s        * Nc + n) * HDc + c8, Rs + wave * 512);
    async_ld16(routerb + ((size_t)(s + 32) * Nc + n) * HDc + c8, Rs + 2048 + wave * 512);
  }
  __syncthreads();
  // build R^T in LDS (one-time, scalar)
  for (int i = 0; i < 16; ++i) {
    int idx = tid * 16 + i;                  // 0..4095
    RTs[(idx & 63) * 64 + (idx >> 6)] = Rs[idx];
  }
  __syncthreads();

  // B-fragments, shared across all m-tiles of the wave
  bf16x8 bs[4][2], br[4][2];
#pragma unroll
  for (int t = 0; t < 4; ++t)
#pragma unroll
    for (int kc = 0; kc < 2; ++kc) {
      bs[t][kc] = *(const bf16x8*)(Rs  + (t * 16 + la) * 64 + kc * 32 + lb8);
      br[t][kc] = *(const bf16x8*)(RTs + (t * 16 + la) * 64 + kc * 32 + lb8);
    }

  unsigned short* ATw = AT + wave * (16 * 64);

  for (int it = 0; it < 8; ++it) {
    const int bidx = wave * 8 + it;          // batch index == m-tile index
    // A-frags straight from global (each q element used exactly once)
    const unsigned short* qrow = qb + ((size_t)(bidx * Nc + n)) * Dc + la * 64;
    bf16x8 aq0 = *(const bf16x8*)(qrow + lb8);
    bf16x8 aq1 = *(const bf16x8*)(qrow + 32 + lb8);

    f32x4 sacc[4] = {};
#pragma unroll
    for (int t = 0; t < 4; ++t) {
      sacc[t] = __builtin_amdgcn_mfma_f32_16x16x32_bf16(aq0, bs[t][0], sacc[t], 0, 0, 0);
      sacc[t] = __builtin_amdgcn_mfma_f32_16x16x32_bf16(aq1, bs[t][1], sacc[t], 0, 0, 0);
    }

    // row softmax: row = 4*(lane>>4)+r; its 64 s-values live in 16 lanes x 4 tiles
#pragma unroll
    for (int r = 0; r < 4; ++r) {
      float mx = fmaxf(fmaxf(sacc[0][r], sacc[1][r]), fmaxf(sacc[2][r], sacc[3][r]));
#pragma unroll
      for (int off = 1; off < 16; off <<= 1) mx = fmaxf(mx, __shfl_xor(mx, off));
      float e0 = __expf(sacc[0][r] - mx), e1 = __expf(sacc[1][r] - mx);
      float e2 = __expf(sacc[2][r] - mx), e3 = __expf(sacc[3][r] - mx);
      float sum = e0 + e1 + e2 + e3;
#pragma unroll
      for (int off = 1; off < 16; off <<= 1) sum += __shfl_xor(sum, off);
      float inv = 1.0f / sum;
      e0 *= inv; e1 *= inv; e2 *= inv; e3 *= inv;

      const int hrow = (lane >> 4) * 4 + r;
      const size_t m = (size_t)bidx * 16 + hrow;
      float* ao = attn_out + (m * Nc + n) * SEGc + la;
      ao[0] = e0; ao[16] = e1; ao[32] = e2; ao[48] = e3;
      unsigned short* aw = ATw + hrow * 64 + la;
      aw[0] = bf16r(e0); aw[16] = bf16r(e1); aw[32] = bf16r(e2); aw[48] = bf16r(e3);
    }

    // C-layout -> A-layout via wave-private LDS round-trip
    __asm__ volatile("s_waitcnt lgkmcnt(0)" ::: "memory");
    bf16x8 ar0 = *(const bf16x8*)(ATw + la * 64 + lb8);
    bf16x8 ar1 = *(const bf16x8*)(ATw + la * 64 + 32 + lb8);

    f32x4 racc[4] = {};
#pragma unroll
    for (int t = 0; t < 4; ++t) {
      racc[t] = __builtin_amdgcn_mfma_f32_16x16x32_bf16(ar0, br[t][0], racc[t], 0, 0, 0);
      racc[t] = __builtin_amdgcn_mfma_f32_16x16x32_bf16(ar1, br[t][1], racc[t], 0, 0, 0);
    }

    // write received bf16: recv[(b*N+n)][h*64+d]
#pragma unroll
    for (int r = 0; r < 4; ++r) {
      const int h = (lane >> 4) * 4 + r;
      unsigned short* ro = recv_out + ((size_t)(bidx * Nc + n)) * Dc + h * 64 + la;
#pragma unroll
      for (int t = 0; t < 4; ++t) ro[t * 16] = bf16r(racc[t][r]);
    }
  }
}

// ---------------------------------------------------------------- launch
extern "C" void kernel_launch(void* const* d_in, const int* in_sizes, int n_in,
                              void* d_out, int out_size, void* d_ws, size_t ws_size,
                              hipStream_t stream) {
  const float* query  = (const float*)d_in[0];
  const float* router = (const float*)d_in[3];
  const float* Wq     = (const float*)d_in[4];
  const float* bq     = (const float*)d_in[5];
  const float* Wo     = (const float*)d_in[10];
  const float* bo     = (const float*)d_in[11];

  float* out      = (float*)d_out;                       // (B,N,D) f32
  float* attn_out = out + (size_t)Bc * Nc * Dc;          // (B,H,N,S) f32

  char* ws = (char*)d_ws;
  unsigned short* query_b  = (unsigned short*)(ws);                       // 32 MiB
  unsigned short* q_b      = (unsigned short*)(ws + 33554432);            // 32 MiB
  unsigned short* recv_b   = (unsigned short*)(ws + 2u * 33554432);       // 32 MiB
  unsigned short* router_b = (unsigned short*)(ws + 3u * 33554432);       // 4 MiB
  unsigned short* WqT      = (unsigned short*)(ws + 3u * 33554432 + 4194304);
  unsigned short* WoT      = (unsigned short*)(ws + 3u * 33554432 + 4194304 + 2097152);

  cvt_bf16<<<16384, 256, 0, stream>>>(query,  query_b,  (Mrows * Dc) / 4);
  cvt_bf16<<<2048,  256, 0, stream>>>(router, router_b, (SEGc * Nc * HDc) / 4);
  transpose_bf16<<<1024, 256, 0, stream>>>(Wq, WqT);
  transpose_bf16<<<1024, 256, 0, stream>>>(Wo, WoT);

  gemm_bt<false><<<(Mrows / 128) * 8, 256, 0, stream>>>(query_b, WqT, bq, q_b);
  router_mid<<<Nc, 256, 0, stream>>>(q_b, router_b, attn_out, recv_b);
  gemm_bt<true ><<<(Mrows / 128) * 8, 256, 0, stream>>>(recv_b, WoT, bo, out);
}

// Round 2
// 399.896 us; speedup vs baseline: 1.0023x; 1.0023x over previous
//
#include <hip/hip_runtime.h>

#define DEV __device__ __forceinline__

typedef __attribute__((ext_vector_type(8))) short bf16x8;   // 8 bf16 in 4 VGPRs
typedef __attribute__((ext_vector_type(4))) float f32x4;

constexpr int Bc  = 32;
constexpr int Nc  = 512;
constexpr int Dc  = 1024;
constexpr int Hc  = 16;
constexpr int HDc = 64;
constexpr int SEGc= 64;
constexpr int Mrows = Bc * Nc;          // 16384 rows for the big GEMMs

// round-to-nearest-even f32 -> bf16 bit pattern
DEV unsigned short bf16r(float x) {
  union { float f; unsigned int u; } c; c.f = x;
  unsigned int r = (c.u + 0x7fffu + ((c.u >> 16) & 1u)) >> 16;
  return (unsigned short)r;
}

// async global->LDS, 16B per lane. LDS dest must be wave-uniform base; HW
// scatters lane i to base + i*16 (guide §5 caveat m104/m108).
DEV void async_ld16(const void* g, void* l) {
  __builtin_amdgcn_global_load_lds(
      (const __attribute__((address_space(1))) void*)g,
      (__attribute__((address_space(3))) void*)l,
      16, 0, 0);
}

// ---------------------------------------------------------------- converts
__global__ void cvt_bf16(const float* __restrict__ src,
                         unsigned short* __restrict__ dst, int n4) {
  int i = blockIdx.x * blockDim.x + threadIdx.x;
  if (i >= n4) return;
  float4 v = ((const float4*)src)[i];
  ushort4 o;
  o.x = bf16r(v.x); o.y = bf16r(v.y); o.z = bf16r(v.z); o.w = bf16r(v.w);
  ((ushort4*)dst)[i] = o;
}

// transpose 1024x1024 f32 -> bf16 (dst[c][r] = src[r][c])
__global__ void transpose_bf16(const float* __restrict__ src,
                               unsigned short* __restrict__ dst) {
  __shared__ float tile[32][33];
  int bx = blockIdx.x & 31, by = blockIdx.x >> 5;
  int tx = threadIdx.x & 31, ty = threadIdx.x >> 5;   // 32 x 8
  for (int i = 0; i < 4; ++i) {
    int r = ty + i * 8;
    tile[r][tx] = src[(size_t)(by * 32 + r) * 1024 + bx * 32 + tx];
  }
  __syncthreads();
  for (int i = 0; i < 4; ++i) {
    int r = ty + i * 8;
    dst[(size_t)(bx * 32 + r) * 1024 + by * 32 + tx] = bf16r(tile[tx][r]);
  }
}

// ---------------------------------------------------------------- GEMM
// C(M x 1024) = A(M x 1024, bf16 row-major) * B + bias; B given as BT (1024 x 1024
// bf16 row-major, BT[n][k] = B[k][n]). OUT_F32: f32 out, else bf16 out.
template <bool OUT_F32>
__global__ __launch_bounds__(256)
void gemm_bt(const unsigned short* __restrict__ A,
             const unsigned short* __restrict__ BT,
             const float* __restrict__ bias,
             void* __restrict__ Cout) {
  constexpr int K = 1024, Nn = 1024, BM = 128, BN = 128, BK = 32;
  __shared__ unsigned short As[BM * BK];   // 8 KB, row-major [128][32]
  __shared__ unsigned short Bs[BN * BK];   // 8 KB, row-major [128][32] (rows = n)
  const int tid = threadIdx.x, lane = tid & 63, wave = tid >> 6;
  const int tm = blockIdx.x >> 3, tn = blockIdx.x & 7;   // Nn/BN = 8
  const int wm = (wave >> 1) * 64, wn = (wave & 1) * 64; // 2x2 waves, 64x64 each
  const int la = lane & 15, quad = lane >> 4, lb8 = quad * 8;

  f32x4 acc[4][4] = {};

  const int srow = tid >> 2;          // 0..63 (staging row, pass 0)
  const int scol = (tid & 3) * 8;     // element col offset (16B chunks)
  const unsigned short* Ag = A  + (size_t)(tm * BM + srow) * K + scol;
  const unsigned short* Bg = BT + (size_t)(tn * BN + srow) * K + scol;
  unsigned short* ldsA = As + wave * 512;   // wave-uniform base (bytes wave*1024)
  unsigned short* ldsB = Bs + wave * 512;

  for (int k0 = 0; k0 < K; k0 += BK) {
    __syncthreads();                       // prev tile fully consumed
    async_ld16(Ag + k0,          ldsA);
    async_ld16(Ag + 64 * K + k0, ldsA + 2048);
    async_ld16(Bg + k0,          ldsB);
    async_ld16(Bg + 64 * K + k0, ldsB + 2048);
    __syncthreads();                       // vmcnt(0) drain before barrier

    bf16x8 af[4], bfr[4];
#pragma unroll
    for (int i = 0; i < 4; ++i)
      af[i] = *(const bf16x8*)(As + (wm + i * 16 + la) * BK + lb8);
#pragma unroll
    for (int j = 0; j < 4; ++j)
      bfr[j] = *(const bf16x8*)(Bs + (wn + j * 16 + la) * BK + lb8);
#pragma unroll
    for (int i = 0; i < 4; ++i)
#pragma unroll
      for (int j = 0; j < 4; ++j)
        acc[i][j] = __builtin_amdgcn_mfma_f32_16x16x32_bf16(af[i], bfr[j],
                                                            acc[i][j], 0, 0, 0);
  }

  // ---- epilogue: LDS-staged coalesced stores --------------------------
  // C/D layout row = quad*4 + r, col = la (m89-verified). Stage each 16x64
  // wave-subtile as f32 in LDS (4 KB/wave, reusing As/Bs), then emit dense
  // float4 / ushort4 stores.
  const int colbase = tn * BN + wn;
  float bv[4];
#pragma unroll
  for (int j = 0; j < 4; ++j) bv[j] = bias[colbase + j * 16 + la];

  float* eps = (wave < 2) ? ((float*)As) + wave * 1024
                          : ((float*)Bs) + (wave - 2) * 1024;
  const int rowbase = tm * BM + wm;

#pragma unroll
  for (int i = 0; i < 4; ++i) {
    __syncthreads();                 // prior LDS users (k-loop / prev i) done
#pragma unroll
    for (int j = 0; j < 4; ++j)
#pragma unroll
      for (int r = 0; r < 4; ++r)
        eps[(quad * 4 + r) * 64 + j * 16 + la] = acc[i][j][r] + bv[j];
    __syncthreads();
#pragma unroll
    for (int s = 0; s < 4; ++s) {
      int idx = s * 64 + lane;       // 0..255
      int row = idx >> 4, c4 = idx & 15;
      float4 v = *(const float4*)(eps + row * 64 + c4 * 4);
      size_t goff = (size_t)(rowbase + i * 16 + row) * Nn + colbase + c4 * 4;
      if (OUT_F32) {
        *(float4*)((float*)Cout + goff) = v;
      } else {
        ushort4 u;
        u.x = bf16r(v.x); u.y = bf16r(v.y); u.z = bf16r(v.z); u.w = bf16r(v.w);
        *(ushort4*)((unsigned short*)Cout + goff) = u;
      }
    }
  }
}

// ---------------------------------------------------------------- middle
// Two blocks per n (b-range split). scores = Q_n(512x64) @ R_n^T ; softmax
// over s ; recv = A @ R_n. Q rows m = b*16+h; one m-tile (16 rows) = one b.
__global__ __launch_bounds__(256)
void router_mid(const unsigned short* __restrict__ qb,       // (16384 x 1024) bf16
                const unsigned short* __restrict__ routerb,  // (64 x 512 x 64) bf16
                float* __restrict__ attn_out,                // (B,H,N,S) f32
                unsigned short* __restrict__ recv_out) {     // (16384 x 1024) bf16
  __shared__ unsigned short Rs [SEGc * HDc];   // 8 KB  R[s][d]
  __shared__ unsigned short RTs[HDc * SEGc];   // 8 KB  R^T[d][s]
  __shared__ unsigned short AT [4 * 16 * 64];  // 8 KB  per-wave bf16 tile
  __shared__ float          FW [4 * 16 * 64];  // 16 KB per-wave f32 attn tile

  const int n = blockIdx.x >> 1, half = blockIdx.x & 1;
  const int tid = threadIdx.x, lane = tid & 63, wave = tid >> 6;
  const int la = lane & 15, quad = lane >> 4, lb8 = quad * 8;

  // stage R: rows s, 64 bf16 each; async 16B/lane, 2 passes
  {
    int c8 = (tid & 7) * 8;
    int s  = tid >> 3;             // 0..31
    async_ld16(routerb + ((size_t)s        * Nc + n) * HDc + c8, Rs + wave * 512);
    async_ld16(routerb + ((size_t)(s + 32) * Nc + n) * HDc + c8, Rs + 2048 + wave * 512);
  }
  __syncthreads();
  // build R^T in LDS (one-time)
  for (int i = 0; i < 16; ++i) {
    int idx = tid * 16 + i;                  // 0..4095
    RTs[(idx & 63) * 64 + (idx >> 6)] = Rs[idx];
  }
  __syncthreads();

  // B-fragments, shared across all m-tiles of the wave
  bf16x8 bs[4][2], br[4][2];
#pragma unroll
  for (int t = 0; t < 4; ++t)
#pragma unroll
    for (int kc = 0; kc < 2; ++kc) {
      bs[t][kc] = *(const bf16x8*)(Rs  + (t * 16 + la) * 64 + kc * 32 + lb8);
      br[t][kc] = *(const bf16x8*)(RTs + (t * 16 + la) * 64 + kc * 32 + lb8);
    }

  unsigned short* ATw = AT + wave * 1024;
  float*          FWw = FW + wave * 1024;

  for (int it = 0; it < 4; ++it) {
    const int bidx = half * 16 + wave * 4 + it;   // batch index == m-tile index
    // A-frags straight from global (each q element used exactly once)
    const unsigned short* qrow = qb + ((size_t)(bidx * Nc + n)) * Dc + la * 64;
    bf16x8 aq0 = *(const bf16x8*)(qrow + lb8);
    bf16x8 aq1 = *(const bf16x8*)(qrow + 32 + lb8);

    f32x4 sacc[4] = {};
#pragma unroll
    for (int t = 0; t < 4; ++t) {
      sacc[t] = __builtin_amdgcn_mfma_f32_16x16x32_bf16(aq0, bs[t][0], sacc[t], 0, 0, 0);
      sacc[t] = __builtin_amdgcn_mfma_f32_16x16x32_bf16(aq1, bs[t][1], sacc[t], 0, 0, 0);
    }

    // row softmax: row = 4*quad+r; its 64 s-values live in 16 lanes x 4 tiles
#pragma unroll
    for (int r = 0; r < 4; ++r) {
      float mx = fmaxf(fmaxf(sacc[0][r], sacc[1][r]), fmaxf(sacc[2][r], sacc[3][r]));
#pragma unroll
      for (int off = 1; off < 16; off <<= 1) mx = fmaxf(mx, __shfl_xor(mx, off));
      float e0 = __expf(sacc[0][r] - mx), e1 = __expf(sacc[1][r] - mx);
      float e2 = __expf(sacc[2][r] - mx), e3 = __expf(sacc[3][r] - mx);
      float sum = e0 + e1 + e2 + e3;
#pragma unroll
      for (int off = 1; off < 16; off <<= 1) sum += __shfl_xor(sum, off);
      float inv = 1.0f / sum;
      e0 *= inv; e1 *= inv; e2 *= inv; e3 *= inv;

      const int hrow = quad * 4 + r;
      float* fw = FWw + hrow * 64 + la;
      fw[0] = e0; fw[16] = e1; fw[32] = e2; fw[48] = e3;
      unsigned short* aw = ATw + hrow * 64 + la;
      aw[0] = bf16r(e0); aw[16] = bf16r(e1); aw[32] = bf16r(e2); aw[48] = bf16r(e3);
    }

    // C-layout -> A-layout via wave-private LDS round-trip
    __asm__ volatile("s_waitcnt lgkmcnt(0)" ::: "memory");
    bf16x8 ar0 = *(const bf16x8*)(ATw + la * 64 + lb8);
    bf16x8 ar1 = *(const bf16x8*)(ATw + la * 64 + 32 + lb8);

    f32x4 racc[4] = {};
#pragma unroll
    for (int t = 0; t < 4; ++t) {
      racc[t] = __builtin_amdgcn_mfma_f32_16x16x32_bf16(ar0, br[t][0], racc[t], 0, 0, 0);
      racc[t] = __builtin_amdgcn_mfma_f32_16x16x32_bf16(ar1, br[t][1], racc[t], 0, 0, 0);
    }

    // attn: 16 rows x 64 f32; row (m) islands of 256B, vectorized float4
#pragma unroll
    for (int s = 0; s < 4; ++s) {
      int idx = s * 64 + lane;         // 0..255
      int row = idx >> 4, c4 = idx & 15;
      float4 v = *(const float4*)(FWw + row * 64 + c4 * 4);
      *(float4*)(attn_out + ((size_t)(bidx * 16 + row) * Nc + n) * SEGc + c4 * 4) = v;
    }

    // recv: the whole m-tile is ONE contiguous 2 KB global row (b,n).
    // Stage racc as bf16 in ATw (A-frags already consumed), then 16B stores.
#pragma unroll
    for (int r = 0; r < 4; ++r) {
      const int h = quad * 4 + r;
      unsigned short* aw = ATw + h * 64 + la;
#pragma unroll
      for (int t = 0; t < 4; ++t) aw[t * 16] = bf16r(racc[t][r]);
    }
    __asm__ volatile("s_waitcnt lgkmcnt(0)" ::: "memory");
    unsigned short* ro = recv_out + ((size_t)(bidx * Nc + n)) * Dc;
#pragma unroll
    for (int s = 0; s < 2; ++s)
      *(bf16x8*)(ro + s * 512 + lane * 8) = *(const bf16x8*)(ATw + s * 512 + lane * 8);
  }
}

// ---------------------------------------------------------------- launch
extern "C" void kernel_launch(void* const* d_in, const int* in_sizes, int n_in,
                              void* d_out, int out_size, void* d_ws, size_t ws_size,
                              hipStream_t stream) {
  const float* query  = (const float*)d_in[0];
  const float* router = (const float*)d_in[3];
  const float* Wq     = (const float*)d_in[4];
  const float* bq     = (const float*)d_in[5];
  const float* Wo     = (const float*)d_in[10];
  const float* bo     = (const float*)d_in[11];

  float* out      = (float*)d_out;                       // (B,N,D) f32
  float* attn_out = out + (size_t)Bc * Nc * Dc;          // (B,H,N,S) f32

  char* ws = (char*)d_ws;
  unsigned short* query_b  = (unsigned short*)(ws);                       // 32 MiB
  unsigned short* q_b      = (unsigned short*)(ws + 33554432);            // 32 MiB
  unsigned short* recv_b   = (unsigned short*)(ws + 2u * 33554432);       // 32 MiB
  unsigned short* router_b = (unsigned short*)(ws + 3u * 33554432);       // 4 MiB
  unsigned short* WqT      = (unsigned short*)(ws + 3u * 33554432 + 4194304);
  unsigned short* WoT      = (unsigned short*)(ws + 3u * 33554432 + 4194304 + 2097152);

  cvt_bf16<<<16384, 256, 0, stream>>>(query,  query_b,  (Mrows * Dc) / 4);
  cvt_bf16<<<2048,  256, 0, stream>>>(router, router_b, (SEGc * Nc * HDc) / 4);
  transpose_bf16<<<1024, 256, 0, stream>>>(Wq, WqT);
  transpose_bf16<<<1024, 256, 0, stream>>>(Wo, WoT);

  gemm_bt<false><<<(Mrows / 128) * 8, 256, 0, stream>>>(query_b, WqT, bq, q_b);
  router_mid<<<2 * Nc, 256, 0, stream>>>(q_b, router_b, attn_out, recv_b);
  gemm_bt<true ><<<(Mrows / 128) * 8, 256, 0, stream>>>(recv_b, WoT, bo, out);
}